// Round 4
// baseline (338.069 us; speedup 1.0000x reference)
//
#include <hip/hip_runtime.h>
#include <hip/hip_bf16.h>
#include <stdint.h>

// B=4, N=8192, E=1024, D=64 ; ROWS = 32768
// out = ((x@wq^T) @ (K^T V) * sqrt(3/64)) @ wo^T
// Precision: weights exact in bf16; activations split hi/lo bf16 -> fp32 MFMA acc.
//
// R4: latency-tolerance rebuild.
//  - K1: raw s_barrier + lgkmcnt-only (x prefetch loads stay in flight across
//    barriers), 2-deep x prefetch.
//  - K2: 1 barrier, conflict-free broadcast inner loop.
//  - K3 split: ctx_kernel (tiny) + out_kernel (barrier-free streaming GEMM,
//    16384 independent waves).

typedef __bf16 bf16x8 __attribute__((ext_vector_type(8)));
typedef float  f32x4  __attribute__((ext_vector_type(4)));

#define MFMA_BF16(A, Bb, C) __builtin_amdgcn_mfma_f32_16x16x32_bf16(A, Bb, C, 0, 0, 0)

__device__ __forceinline__ int swz8(int row, int slot) { return (slot ^ (row & 7)) << 3; }

// LDS-only barrier: waits LDS ops, leaves global loads in flight (T4).
__device__ __forceinline__ void lds_barrier() {
    asm volatile("s_waitcnt lgkmcnt(0)" ::: "memory");
    __builtin_amdgcn_s_barrier();
}

// ---------------------------------------------------------------------------
// P0: flat fp32->bf16 cast of [wq|wk|wv|wo] -> Wb[192][1024] ++ Wob[1024][64].
// ---------------------------------------------------------------------------
__global__ __launch_bounds__(128) void prep_kernel(
    const float* __restrict__ wq, const float* __restrict__ wk,
    const float* __restrict__ wv, const float* __restrict__ wo,
    __bf16* __restrict__ Wb)
{
    const int gid = blockIdx.x * 128 + threadIdx.x;      // 0..32767
    const int e0  = gid * 8;
    const float* src = (e0 < 65536)  ? wq + e0
                     : (e0 < 131072) ? wk + (e0 - 65536)
                     : (e0 < 196608) ? wv + (e0 - 131072)
                                     : wo + (e0 - 196608);
    float w[8];
    *(float4*)&w[0] = *(const float4*)(src);
    *(float4*)&w[4] = *(const float4*)(src + 4);
    bf16x8 wb;
#pragma unroll
    for (int j = 0; j < 8; ++j) wb[j] = (__bf16)w[j];
    *(bf16x8*)&Wb[e0] = wb;
}

// ---------------------------------------------------------------------------
// K1: QKV GEMM.  C[32768 x 192] = split(x) @ Wb^T.
// 1024 blocks x 256 thr (4 waves = 4 col groups of 48), tile 32r, BK=64.
// 2-deep x prefetch; lds_barrier() keeps prefetch alive across steps.
// ---------------------------------------------------------------------------
__global__ __launch_bounds__(256) void qkv_kernel(
    const float* __restrict__ x, const __bf16* __restrict__ Wb,
    float* __restrict__ Qf, float* __restrict__ Kf, float* __restrict__ Vf)
{
    __shared__ __bf16 xh[2][32 * 64];
    __shared__ __bf16 xl[2][32 * 64];

    const int tid  = threadIdx.x;
    const int lane = tid & 63;
    const int wid  = tid >> 6;          // col group of 48
    const int lr   = lane & 15;
    const int kg   = lane >> 4;
    const int row0 = blockIdx.x * 32;
    const int sr   = tid >> 3;          // staging row 0..31
    const int f8   = tid & 7;           // staging k-slot

    f32x4 acc[2][3];
#pragma unroll
    for (int i = 0; i < 2; ++i)
#pragma unroll
        for (int j = 0; j < 3; ++j) acc[i][j] = (f32x4){0.f, 0.f, 0.f, 0.f};

    const float* xbase = &x[(size_t)(row0 + sr) * 1024 + f8 * 8];
    float xv[8], xn[8], xm[8];
#pragma unroll
    for (int j = 0; j < 8; ++j) xm[j] = 0.f;

#define LOAD_X(dst, stp)                                                       \
    {                                                                          \
        *(float4*)&dst[0] = *(const float4*)(xbase + (stp) * 64);              \
        *(float4*)&dst[4] = *(const float4*)(xbase + (stp) * 64 + 4);          \
    }

    LOAD_X(xv, 0);
    LOAD_X(xn, 1);

    for (int step = 0; step < 16; ++step) {
        const int cur = step & 1;
        // convert xv -> hi/lo, swizzled LDS write
        {
            bf16x8 h, l;
#pragma unroll
            for (int j = 0; j < 8; ++j) {
                const float v = xv[j];
                const unsigned int bb = __float_as_uint(v);
                h[j] = __builtin_bit_cast(__bf16, (unsigned short)(bb >> 16));
                l[j] = (__bf16)(v - __uint_as_float(bb & 0xffff0000u));
            }
            const int off = sr * 64 + swz8(sr, f8);
            *(bf16x8*)&xh[cur][off] = h;
            *(bf16x8*)&xl[cur][off] = l;
        }
        lds_barrier();                       // LDS visible; x-prefetch stays in flight
        if (step < 14) LOAD_X(xm, step + 2); // 2 phases + barrier of cover

#pragma unroll
        for (int ks = 0; ks < 2; ++ks) {
            const int slot = ks * 4 + kg;
            bf16x8 Ah[2], Al[2], Bw[3];
#pragma unroll
            for (int bn = 0; bn < 3; ++bn) {
                const int col = wid * 48 + bn * 16 + lr;
                Bw[bn] = *(const bf16x8*)&Wb[(size_t)col * 1024 + step * 64 + slot * 8];
            }
#pragma unroll
            for (int am = 0; am < 2; ++am) {
                const int row = am * 16 + lr;
                Ah[am] = *(const bf16x8*)&xh[cur][row * 64 + swz8(row, slot)];
                Al[am] = *(const bf16x8*)&xl[cur][row * 64 + swz8(row, slot)];
            }
#pragma unroll
            for (int am = 0; am < 2; ++am)
#pragma unroll
                for (int bn = 0; bn < 3; ++bn) {
                    acc[am][bn] = MFMA_BF16(Ah[am], Bw[bn], acc[am][bn]);
                    acc[am][bn] = MFMA_BF16(Al[am], Bw[bn], acc[am][bn]);
                }
        }
#pragma unroll
        for (int j = 0; j < 8; ++j) { xv[j] = xn[j]; xn[j] = xm[j]; }
    }
#undef LOAD_X

    // epilogue: C/D layout col=lane&15, row=(lane>>4)*4+reg
#pragma unroll
    for (int am = 0; am < 2; ++am)
#pragma unroll
        for (int bn = 0; bn < 3; ++bn) {
            const int col  = wid * 48 + bn * 16 + lr;
            const int rowb = row0 + am * 16 + kg * 4;
            float* dst = (col < 64) ? Qf : (col < 128) ? Kf : Vf;
            const int cc = col & 63;
#pragma unroll
            for (int r = 0; r < 4; ++r)
                dst[(size_t)(rowb + r) * 64 + cc] = acc[am][bn][r];
        }
}

// ---------------------------------------------------------------------------
// K2: partial energy.  part[blk][d][e] = sum over 64 rows of K[n,d]*V[n,e].
// 512 blocks x 256 thr; 1 barrier; d=lane (stride-1 LDS), V reads broadcast.
// ---------------------------------------------------------------------------
__global__ __launch_bounds__(256) void energy_partial_kernel(
    const float* __restrict__ Kf, const float* __restrict__ Vf,
    float* __restrict__ part)
{
    __shared__ float lK[64 * 64];
    __shared__ float lV[64 * 64];
    const int tid  = threadIdx.x;
    const int row0 = blockIdx.x * 64;

#pragma unroll
    for (int i = 0; i < 4; ++i) {
        const int idx = tid + i * 256;           // float4 slot 0..1023
        const int r   = idx >> 4;
        const int c4  = (idx & 15) << 2;
        *(float4*)&lK[r * 64 + c4] = *(const float4*)&Kf[(size_t)(row0 + r) * 64 + c4];
        *(float4*)&lV[r * 64 + c4] = *(const float4*)&Vf[(size_t)(row0 + r) * 64 + c4];
    }
    __syncthreads();

    const int d  = tid & 63;                     // lane -> stride-1 LDS reads
    const int eb = (tid >> 6) * 16;              // wave's e-block
    float acc[16];
#pragma unroll
    for (int j = 0; j < 16; ++j) acc[j] = 0.f;

    for (int n = 0; n < 64; ++n) {
        const float kd = lK[n * 64 + d];
        const float4 v0 = *(const float4*)&lV[n * 64 + eb];
        const float4 v1 = *(const float4*)&lV[n * 64 + eb + 4];
        const float4 v2 = *(const float4*)&lV[n * 64 + eb + 8];
        const float4 v3 = *(const float4*)&lV[n * 64 + eb + 12];
        acc[0]  += kd * v0.x; acc[1]  += kd * v0.y; acc[2]  += kd * v0.z; acc[3]  += kd * v0.w;
        acc[4]  += kd * v1.x; acc[5]  += kd * v1.y; acc[6]  += kd * v1.z; acc[7]  += kd * v1.w;
        acc[8]  += kd * v2.x; acc[9]  += kd * v2.y; acc[10] += kd * v2.z; acc[11] += kd * v2.w;
        acc[12] += kd * v3.x; acc[13] += kd * v3.y; acc[14] += kd * v3.z; acc[15] += kd * v3.w;
    }
    float* p = part + (size_t)blockIdx.x * 4096 + d * 64 + eb;
#pragma unroll
    for (int i = 0; i < 4; ++i)
        *(float4*)&p[i * 4] = make_float4(acc[i*4], acc[i*4+1], acc[i*4+2], acc[i*4+3]);
}

// K2b: reduce 128 partials per batch, fold sqrt(3/64), emit E^T hi/lo bf16
// plain layout Et[b][e*64+d] (B-frag for ctx GEMM reads 8 contiguous d).
__global__ __launch_bounds__(256) void energy_reduce_kernel(
    const float* __restrict__ part, __bf16* __restrict__ Eth, __bf16* __restrict__ Etl)
{
    const int b    = blockIdx.x >> 4;
    const int elem = ((blockIdx.x & 15) << 8) + threadIdx.x;   // d*64+e
    float s = 0.f;
#pragma unroll 8
    for (int c = 0; c < 128; ++c)
        s += part[(size_t)(b * 128 + c) * 4096 + elem];
    s *= 0.2165063509461097f;                                  // sqrt(3/64)
    const int d = elem >> 6, e = elem & 63;
    const __bf16 h = (__bf16)s;
    const __bf16 l = (__bf16)(s - (float)h);
    const size_t o = (size_t)b * 4096 + e * 64 + d;
    Eth[o] = h; Etl[o] = l;
}

// ---------------------------------------------------------------------------
// K3a: ctx = Q @ E -> bf16 hi/lo row-major [32768][64].
// 512 blocks x 256 thr; each wave owns 16 rows; per-wave LDS transpose.
// ---------------------------------------------------------------------------
__global__ __launch_bounds__(256) void ctx_kernel(
    const float* __restrict__ Qf,
    const __bf16* __restrict__ Eth, const __bf16* __restrict__ Etl,
    __bf16* __restrict__ Ch, __bf16* __restrict__ Cl)
{
    __shared__ float ct[4][16 * 68];             // padded stride 68

    const int tid  = threadIdx.x;
    const int lane = tid & 63;
    const int wid  = tid >> 6;
    const int lr   = lane & 15;
    const int kg   = lane >> 4;
    const int row0 = blockIdx.x * 64 + wid * 16;
    const int b    = blockIdx.x >> 7;            // 128 blocks per batch

    // A-frags: Q rows row0..+16 direct from global, hi/lo split in-reg
    bf16x8 Qh[2], Ql[2];
#pragma unroll
    for (int ks = 0; ks < 2; ++ks) {
        float qv[8];
        const float* src = &Qf[(size_t)(row0 + lr) * 64 + (ks * 4 + kg) * 8];
        *(float4*)&qv[0] = *(const float4*)(src);
        *(float4*)&qv[4] = *(const float4*)(src + 4);
#pragma unroll
        for (int j = 0; j < 8; ++j) {
            const unsigned int bb = __float_as_uint(qv[j]);
            Qh[ks][j] = __builtin_bit_cast(__bf16, (unsigned short)(bb >> 16));
            Ql[ks][j] = (__bf16)(qv[j] - __uint_as_float(bb & 0xffff0000u));
        }
    }

    f32x4 cacc[4];
#pragma unroll
    for (int i = 0; i < 4; ++i) cacc[i] = (f32x4){0.f, 0.f, 0.f, 0.f};

#pragma unroll
    for (int ks = 0; ks < 2; ++ks) {
        const int slot = ks * 4 + kg;
#pragma unroll
        for (int eb = 0; eb < 4; ++eb) {
            const int e = eb * 16 + lr;
            const bf16x8 Bh = *(const bf16x8*)&Eth[(size_t)b * 4096 + e * 64 + slot * 8];
            const bf16x8 Bl = *(const bf16x8*)&Etl[(size_t)b * 4096 + e * 64 + slot * 8];
            cacc[eb] = MFMA_BF16(Qh[ks], Bh, cacc[eb]);
            cacc[eb] = MFMA_BF16(Qh[ks], Bl, cacc[eb]);
            cacc[eb] = MFMA_BF16(Ql[ks], Bh, cacc[eb]);
        }
    }

    // transpose via wave-private LDS: C layout col=e, row=kg*4+r
#pragma unroll
    for (int eb = 0; eb < 4; ++eb)
#pragma unroll
        for (int r = 0; r < 4; ++r)
            ct[wid][(kg * 4 + r) * 68 + eb * 16 + lr] = cacc[eb][r];
    __syncthreads();

    // read back row-major, split hi/lo, store coalesced
    const int r2 = lane >> 2;                    // 0..15
    const int c8 = (lane & 3) * 16;              // 0,16,32,48
    float f[16];
#pragma unroll
    for (int i = 0; i < 4; ++i)
        *(float4*)&f[i * 4] = *(const float4*)&ct[wid][r2 * 68 + c8 + i * 4];
    bf16x8 h[2], l[2];
#pragma unroll
    for (int g = 0; g < 2; ++g)
#pragma unroll
        for (int j = 0; j < 8; ++j) {
            const float v = f[g * 8 + j];
            const unsigned int bb = __float_as_uint(v);
            h[g][j] = __builtin_bit_cast(__bf16, (unsigned short)(bb >> 16));
            l[g][j] = (__bf16)(v - __uint_as_float(bb & 0xffff0000u));
        }
    const size_t o = (size_t)(row0 + r2) * 64 + c8;
    *(bf16x8*)&Ch[o]     = h[0];
    *(bf16x8*)&Ch[o + 8] = h[1];
    *(bf16x8*)&Cl[o]     = l[0];
    *(bf16x8*)&Cl[o + 8] = l[1];
}

// ---------------------------------------------------------------------------
// K3b: out = ctx @ wo^T.  Pure streaming GEMM: 4096 blocks x 4 waves, each
// wave 16 rows x 128 cols, zero LDS, zero barriers.  A from Ch/Cl, B from
// L2-resident Wob.  32 MFMA + 32 store insts per wave.
// ---------------------------------------------------------------------------
__global__ __launch_bounds__(256) void out_kernel(
    const __bf16* __restrict__ Ch, const __bf16* __restrict__ Cl,
    const __bf16* __restrict__ Wob, float* __restrict__ out)
{
    const int tid  = threadIdx.x;
    const int lane = tid & 63;
    const int wid  = tid >> 6;
    const int lr   = lane & 15;
    const int kg   = lane >> 4;
    const int row0 = (blockIdx.x >> 1) * 16;
    const int c0   = (blockIdx.x & 1) * 512 + wid * 128;

    // A-frags: 16 rows, full K=64
    bf16x8 Ah[2], Al[2];
#pragma unroll
    for (int ks = 0; ks < 2; ++ks) {
        const size_t o = (size_t)(row0 + lr) * 64 + (ks * 4 + kg) * 8;
        Ah[ks] = *(const bf16x8*)&Ch[o];
        Al[ks] = *(const bf16x8*)&Cl[o];
    }

    f32x4 oacc[8];
#pragma unroll
    for (int i = 0; i < 8; ++i) oacc[i] = (f32x4){0.f, 0.f, 0.f, 0.f};

#pragma unroll
    for (int ks = 0; ks < 2; ++ks) {
        const int slot = ks * 4 + kg;
#pragma unroll
        for (int bn = 0; bn < 8; ++bn) {
            const int col = c0 + bn * 16 + lr;
            const bf16x8 Bw = *(const bf16x8*)&Wob[(size_t)col * 64 + slot * 8];
            oacc[bn] = MFMA_BF16(Ah[ks], Bw, oacc[bn]);
            oacc[bn] = MFMA_BF16(Al[ks], Bw, oacc[bn]);
        }
    }

#pragma unroll
    for (int bn = 0; bn < 8; ++bn)
#pragma unroll
        for (int r = 0; r < 4; ++r)
            __builtin_nontemporal_store(oacc[bn][r],
                &out[(size_t)(row0 + kg * 4 + r) * 1024 + c0 + bn * 16 + lr]);
}

extern "C" void kernel_launch(void* const* d_in, const int* in_sizes, int n_in,
                              void* d_out, int out_size, void* d_ws, size_t ws_size,
                              hipStream_t stream)
{
    const float* x  = (const float*)d_in[0];
    const float* wq = (const float*)d_in[1];
    const float* wk = (const float*)d_in[2];
    const float* wv = (const float*)d_in[3];
    const float* wo = (const float*)d_in[4];
    float* out = (float*)d_out;

    char* ws = (char*)d_ws;
    float*  Qf   = (float*)(ws);                          //  8 MB
    float*  Kf   = (float*)(ws + 8388608);                //  8 MB
    float*  Vf   = (float*)(ws + 16777216);               //  8 MB
    float*  part = (float*)(ws + 25165824);               //  8 MB (512*4096*4)
    __bf16* Wb   = (__bf16*)(ws + 33554432);              //  512 KB [192][1024] ++ [1024][64]
    __bf16* Wob  = Wb + 196608;
    __bf16* Eth  = (__bf16*)(ws + 34603008);              //  32 KB
    __bf16* Etl  = (__bf16*)(ws + 34635776);              //  32 KB
    __bf16* Ch   = (__bf16*)(ws + 34668544);              //  4 MB
    __bf16* Cl   = (__bf16*)(ws + 38862848);              //  4 MB

    prep_kernel<<<256, 128, 0, stream>>>(wq, wk, wv, wo, Wb);
    qkv_kernel<<<1024, 256, 0, stream>>>(x, Wb, Qf, Kf, Vf);
    energy_partial_kernel<<<512, 256, 0, stream>>>(Kf, Vf, part);
    energy_reduce_kernel<<<64, 256, 0, stream>>>(part, Eth, Etl);
    ctx_kernel<<<512, 256, 0, stream>>>(Qf, Eth, Etl, Ch, Cl);
    out_kernel<<<4096, 256, 0, stream>>>(Ch, Cl, Wob, out);
}